// Round 10
// baseline (225.248 us; speedup 1.0000x reference)
//
#include <hip/hip_runtime.h>

// Problem constants (from reference)
constexpr int B     = 16384;
constexpr int NNEG  = 10;
constexpr int D     = 8;
constexpr int E     = 64;               // == wavefront: lane l owns dim l
constexpr int ROWS  = B * (1 + NNEG);   // 180224; flat row id == output index
constexpr int RPW   = 4;                // rows per wave, processed in-register

// pair_sum = sum_{i<j} e_i.e_j = 0.5*(||sum_d e_d||^2 - sum_d ||e_d||^2).
//
// Round-3 structure (empirical roofline: 1.44M random row-gathers at the
// measured ~33G rows/s address-service wall + 369MB at ~14TB/s byte wall
// = ~70us kernel; verified invariant across 5 structures in rounds 1-9).
// This round's only delta: non-temporal gathers (skip L2 allocation; table
// is 128MB random-access, L2 hit ~3% -- allocation is near-pure overhead).
__global__ __launch_bounds__(256) void APE_61555471286335_kernel(
    const int*   __restrict__ pos_x,   // [B, D]
    const int*   __restrict__ neg_x,   // [B, NNEG, D]
    const float* __restrict__ emb,     // [N_ENT, E]
    const float* __restrict__ pair_w,  // [N_PAIRS]
    const float* __restrict__ c,       // [1]
    float*       __restrict__ out)     // [ROWS]
{
    const int tid  = blockIdx.x * blockDim.x + threadIdx.x;
    const int wave = tid >> 6;
    const int lane = threadIdx.x & 63;
    const int row0 = wave * RPW;       // exact grid, no bounds check

    // Gather 4 rows x 8 dims = 32 coalesced 256B row-reads, back-to-back.
    float v[RPW][D];
#pragma unroll
    for (int r = 0; r < RPW; ++r) {
        const int row = row0 + r;
        const int* idx = (row < B) ? (pos_x + (size_t)row * D)
                                   : (neg_x + (size_t)(row - B) * D);
#pragma unroll
        for (int d = 0; d < D; ++d)
            v[r][d] = __builtin_nontemporal_load(
                emb + (size_t)idx[d] * E + lane);
    }

    // Per-row fused partial: p = s^2 - ss  (per-lane).
    float p[RPW];
#pragma unroll
    for (int r = 0; r < RPW; ++r) {
        float s = 0.f, ss = 0.f;
#pragma unroll
        for (int d = 0; d < D; ++d) {
            s  += v[r][d];
            ss += v[r][d] * v[r][d];
        }
        p[r] = s * s - ss;
    }

    // One butterfly per row; afterwards every lane holds the row's total.
#pragma unroll
    for (int off = 32; off > 0; off >>= 1) {
#pragma unroll
        for (int r = 0; r < RPW; ++r)
            p[r] += __shfl_xor(p[r], off, 64);
    }

    if (lane == 0) {
        const float w  = expf(pair_w[0]);
        const float cc = c[0];
#pragma unroll
        for (int r = 0; r < RPW; ++r)
            out[row0 + r] = expf(0.5f * p[r] * w + cc);
    }
}

extern "C" void kernel_launch(void* const* d_in, const int* in_sizes, int n_in,
                              void* d_out, int out_size, void* d_ws, size_t ws_size,
                              hipStream_t stream) {
    const int*   pos_x  = (const int*)  d_in[0];
    const int*   neg_x  = (const int*)  d_in[1];
    const float* emb    = (const float*)d_in[2];
    const float* pair_w = (const float*)d_in[3];
    const float* c      = (const float*)d_in[4];
    float*       out    = (float*)      d_out;

    constexpr int BLOCK = 256;                          // 4 waves/block
    constexpr int ROWS_PER_BLOCK = (BLOCK / 64) * RPW;  // 16
    static_assert(ROWS % ROWS_PER_BLOCK == 0, "exact grid");
    const int grid = ROWS / ROWS_PER_BLOCK;             // 11264

    APE_61555471286335_kernel<<<grid, BLOCK, 0, stream>>>(
        pos_x, neg_x, emb, pair_w, c, out);
}